// Round 4
// baseline (1524.765 us; speedup 1.0000x reference)
//
#include <hip/hip_runtime.h>
#include <math.h>

#define NB 4
#define NT 25
#define NN 10000
#define NF 3
#define NC 16
#define NE 160000
#define HID 512
#define NOUT 2
#define FLAT (NN*NC)    // 160000

// head1 split: 500 blocks x 320 rows, 2 half-chunks each -> 1000 partial chunks
#define NHB 500
#define HCHUNK 320
#define NPART (NHB*2)
#define RSPLIT 16
#define RSPAN ((NPART + RSPLIT - 1)/RSPLIT)   // 63

// ---------------- CSR build (deterministic float math: no float atomics) ----------------

__global__ void k_init(int* count, int* cursor) {
    int n = blockIdx.x*blockDim.x + threadIdx.x;
    if (n < NN) { count[n] = 0; cursor[n] = 0; }
}

__global__ void k_count(const int* ei, int* count) {
    int e = blockIdx.x*blockDim.x + threadIdx.x;
    if (e < NE) atomicAdd(&count[ei[NE + e]], 1);
}

__global__ __launch_bounds__(1024) void k_scan(const int* count, int* rowptr) {
    __shared__ int wsum[16];
    __shared__ int carry;
    int tid = threadIdx.x;
    if (tid == 0) { carry = 0; rowptr[0] = 0; }
    __syncthreads();
    for (int base = 0; base < NN; base += 1024) {
        int i = base + tid;
        int v = (i < NN) ? count[i] : 0;
        int lane = tid & 63, wid = tid >> 6;
        int xs = v;
        #pragma unroll
        for (int off = 1; off < 64; off <<= 1) {
            int y = __shfl_up(xs, off);
            if (lane >= off) xs += y;
        }
        if (lane == 63) wsum[wid] = xs;
        __syncthreads();
        if (wid == 0 && lane < 16) {
            int s = wsum[lane];
            #pragma unroll
            for (int off = 1; off < 16; off <<= 1) {
                int y = __shfl_up(s, off);
                if (lane >= off) s += y;
            }
            wsum[lane] = s;
        }
        __syncthreads();
        int prefix = carry + (wid ? wsum[wid-1] : 0);
        if (i < NN) rowptr[i+1] = prefix + xs;
        __syncthreads();
        if (tid == 0) carry += wsum[15];
        __syncthreads();
    }
}

__global__ void k_fill(const int* ei, const float* ew, const int* rowptr,
                       int* cursor, int* col, float* val) {
    int e = blockIdx.x*blockDim.x + threadIdx.x;
    if (e < NE) {
        int src = ei[e];
        int dst = ei[NE + e];
        int p = rowptr[dst] + atomicAdd(&cursor[dst], 1);
        col[p] = src;
        val[p] = ew[e];          // raw weight; normalized after deg
    }
}

__global__ void k_deg(const int* rowptr, const float* val, float* dinv) {
    int n = blockIdx.x*blockDim.x + threadIdx.x;
    if (n >= NN) return;
    float d = 1.0f;              // self loop weight
    int beg = rowptr[n], end = rowptr[n+1];
    for (int j = beg; j < end; ++j) d += val[j];
    dinv[n] = (d > 0.f) ? 1.0f/sqrtf(d) : 0.f;
}

__global__ void k_norm(const int* rowptr, const int* col, const float* dinv, float* val) {
    int n = blockIdx.x*blockDim.x + threadIdx.x;
    if (n >= NN) return;
    float dn = dinv[n];
    int beg = rowptr[n], end = rowptr[n+1];
    for (int j = beg; j < end; ++j) val[j] = dinv[col[j]] * val[j] * dn;
}

// ---------------- x repack: xp[t][n][b] = float4(x[b,t,n,0..2], 0) ----------------
// all 4 batch values of a node in ONE 64B line -> k_agg's gather touches 1 line, not 4.

__global__ __launch_bounds__(256) void k_xpad(const float* x, float4* xp) {
    int idx = blockIdx.x*blockDim.x + threadIdx.x;
    if (idx >= NN*NT) return;
    int n = idx % NN;
    int t = idx / NN;
    #pragma unroll
    for (int b = 0; b < NB; ++b) {
        int base = ((b*NT + t)*NN + n)*NF;
        float4 o; o.x = x[base]; o.y = x[base+1]; o.z = x[base+2]; o.w = 0.f;
        xp[(t*NN + n)*NB + b] = o;
    }
}

// ---------------- aggregation: agg[t][b][n] = (A_hat x_t)[b,n,:] ----------------

__global__ __launch_bounds__(256) void k_agg(const float4* xp, const int* rowptr, const int* col,
                                             const float* val, const float* dinv, float4* agg) {
    int idx = blockIdx.x*blockDim.x + threadIdx.x;
    if (idx >= NN*NT) return;
    int n = idx % NN;
    int t = idx / NN;
    float di = dinv[n];
    float dsq = di*di;                 // self-loop: w=1, norm = dinv[n]^2
    float ax[NB], ay[NB], az[NB];
    int sbase = (t*NN + n)*NB;
    #pragma unroll
    for (int b = 0; b < NB; ++b) {
        float4 v = xp[sbase + b];
        ax[b] = dsq*v.x; ay[b] = dsq*v.y; az[b] = dsq*v.z;
    }
    int beg = rowptr[n], end = rowptr[n+1];
    for (int j = beg; j < end; ++j) {
        int s = col[j];
        float nv = val[j];
        int gb = (t*NN + s)*NB;
        #pragma unroll
        for (int b = 0; b < NB; ++b) {
            float4 v = xp[gb + b];
            ax[b] += nv*v.x; ay[b] += nv*v.y; az[b] += nv*v.z;
        }
    }
    #pragma unroll
    for (int b = 0; b < NB; ++b) {
        float4 o; o.x = ax[b]; o.y = ay[b]; o.z = az[b]; o.w = 0.f;
        agg[(t*NB + b)*NN + n] = o;
    }
}

// ---------------- fused GRU: all 25 steps, H in registers, weights fused in-block ----------------
// sF layout per gate g (base g*320): [0..47] W' = W@L_top (f*16+c),
// [48..63] b' = b@L_top + lb, [64..319] L_bot (k*16+c)

__global__ __launch_bounds__(256) void k_gru_all(
        const float* Wz, const float* bz, const float* Lz, const float* lbz,
        const float* Wr, const float* br, const float* Lr, const float* lbr,
        const float* Wh, const float* bh, const float* Lh, const float* lbh,
        const float4* agg, float* H) {
    __shared__ float sF[960];
    {
        int tid = threadIdx.x;
        const float* W[3]  = {Wz, Wr, Wh};
        const float* bb[3] = {bz, br, bh};
        const float* L[3]  = {Lz, Lr, Lh};
        const float* lb[3] = {lbz, lbr, lbh};
        #pragma unroll
        for (int g = 0; g < 3; ++g) {
            float* outp = sF + g*320;
            if (tid < 48) {
                int f = tid >> 4, c = tid & 15;
                float s = 0.f;
                #pragma unroll
                for (int k = 0; k < 16; ++k) s += W[g][f*16+k] * L[g][k*16+c];
                outp[tid] = s;
            }
            if (tid < 16) {
                float s = 0.f;
                #pragma unroll
                for (int k = 0; k < 16; ++k) s += bb[g][k] * L[g][k*16+tid];
                outp[48+tid] = s + lb[g][tid];
            }
            {
                int k = tid >> 4, c = tid & 15;
                outp[64 + tid] = L[g][(16+k)*16 + c];
            }
        }
    }
    __syncthreads();
    int idx = blockIdx.x*blockDim.x + threadIdx.x;
    if (idx >= NB*NN) return;
    int b = idx / NN, n = idx % NN;
    const float* sWz = sF;       const float* sBz = sF+48;  const float* sLz = sF+64;
    const float* sWr = sF+320;   const float* sBr = sF+368; const float* sLr = sF+384;
    const float* sWh = sF+640;   const float* sBh = sF+688; const float* sLh = sF+704;

    float Hv[16];
    #pragma unroll
    for (int c = 0; c < 16; ++c) Hv[c] = 0.f;

    for (int t = 0; t < NT; ++t) {
        float4 A = agg[(t*NB + b)*NN + n];
        float z[16], r[16], ht[16];
        #pragma unroll
        for (int c = 0; c < 16; ++c) {
            z[c]  = sBz[c] + A.x*sWz[c] + A.y*sWz[16+c] + A.z*sWz[32+c];
            r[c]  = sBr[c] + A.x*sWr[c] + A.y*sWr[16+c] + A.z*sWr[32+c];
            ht[c] = sBh[c] + A.x*sWh[c] + A.y*sWh[16+c] + A.z*sWh[32+c];
        }
        #pragma unroll
        for (int k = 0; k < 16; ++k) {
            float hk = Hv[k];
            #pragma unroll
            for (int c = 0; c < 16; ++c) {
                z[c] += hk * sLz[k*16+c];
                r[c] += hk * sLr[k*16+c];
            }
        }
        #pragma unroll
        for (int c = 0; c < 16; ++c) {
            z[c] = 1.0f / (1.0f + expf(-z[c]));
            r[c] = 1.0f / (1.0f + expf(-r[c]));
        }
        #pragma unroll
        for (int k = 0; k < 16; ++k) {
            float hk = Hv[k] * r[k];
            #pragma unroll
            for (int c = 0; c < 16; ++c) ht[c] += hk * sLh[k*16+c];
        }
        #pragma unroll
        for (int c = 0; c < 16; ++c) {
            float h2 = tanhf(ht[c]);
            Hv[c] = z[c]*Hv[c] + (1.0f - z[c])*h2;
        }
    }
    int hbase = (b*NN + n)*NC;
    #pragma unroll
    for (int c = 0; c < 16; ++c) H[hbase+c] = Hv[c];
}

// ---------------- head: H(4,160000) @ W1(160000,512), split-K, float4 loads ----------------

__global__ __launch_bounds__(256) void k_head1(const float* H, const float* W1, float* part) {
    __shared__ float sH[NB][HCHUNK];
    int chunk = blockIdx.x;
    int i0 = chunk * HCHUNK;
    for (int i = threadIdx.x; i < NB*HCHUNK; i += 256) {
        int b = i / HCHUNK, r = i % HCHUNK;
        sH[b][r] = H[b*FLAT + i0 + r];
    }
    __syncthreads();
    int half = threadIdx.x >> 7;        // which row parity this thread sums
    int jj = (threadIdx.x & 127) * 4;   // column group
    const float* Wb = W1 + (size_t)i0*HID + jj;
    float acc[NB][4] = {};
    // 8 rows per iteration -> 8 outstanding 16B loads per wave (MLP to cover ~900cy HBM latency)
    for (int r0 = half; r0 < HCHUNK; r0 += 16) {
        float4 w0 = *(const float4*)(Wb + (size_t)(r0     )*HID);
        float4 w1 = *(const float4*)(Wb + (size_t)(r0 +  2)*HID);
        float4 w2 = *(const float4*)(Wb + (size_t)(r0 +  4)*HID);
        float4 w3 = *(const float4*)(Wb + (size_t)(r0 +  6)*HID);
        float4 w4 = *(const float4*)(Wb + (size_t)(r0 +  8)*HID);
        float4 w5 = *(const float4*)(Wb + (size_t)(r0 + 10)*HID);
        float4 w6 = *(const float4*)(Wb + (size_t)(r0 + 12)*HID);
        float4 w7 = *(const float4*)(Wb + (size_t)(r0 + 14)*HID);
        #pragma unroll
        for (int b = 0; b < NB; ++b) {
            float h0 = sH[b][r0],    h1 = sH[b][r0+2],  h2 = sH[b][r0+4],  h3 = sH[b][r0+6];
            float h4 = sH[b][r0+8],  h5 = sH[b][r0+10], h6 = sH[b][r0+12], h7 = sH[b][r0+14];
            acc[b][0] += h0*w0.x + h1*w1.x + h2*w2.x + h3*w3.x + h4*w4.x + h5*w5.x + h6*w6.x + h7*w7.x;
            acc[b][1] += h0*w0.y + h1*w1.y + h2*w2.y + h3*w3.y + h4*w4.y + h5*w5.y + h6*w6.y + h7*w7.y;
            acc[b][2] += h0*w0.z + h1*w1.z + h2*w2.z + h3*w3.z + h4*w4.z + h5*w5.z + h6*w6.z + h7*w7.z;
            acc[b][3] += h0*w0.w + h1*w1.w + h2*w2.w + h3*w3.w + h4*w4.w + h5*w5.w + h6*w6.w + h7*w7.w;
        }
    }
    int pc = chunk*2 + half;
    #pragma unroll
    for (int q = 0; q < 4; ++q)
        #pragma unroll
        for (int b = 0; b < NB; ++b)
            part[((size_t)pc*HID + jj + q)*NB + b] = acc[b][q];
}

// phase 1: split the 1000-chunk sum 16 ways (512 waves -> real parallelism)
__global__ void k_reduce1(const float* part, float* part2) {
    int idx = blockIdx.x*blockDim.x + threadIdx.x;   // 0 .. 16*2048-1
    if (idx >= RSPLIT*HID*NB) return;
    int k = idx >> 11;           // split index
    int jb = idx & 2047;
    int c0 = k*RSPAN;
    int c1 = c0 + RSPAN; if (c1 > NPART) c1 = NPART;
    float s = 0.f;
    for (int c = c0; c < c1; ++c) s += part[(size_t)c*(HID*NB) + jb];
    part2[k*(HID*NB) + jb] = s;
}

// phase 2 + final head, one block: h1 = leaky(sum + b1); out = h1 @ W2 + b2
__global__ __launch_bounds__(256) void k_reduce2final(const float* part2, const float* b1,
                                                      const float* W2, const float* b2, float* out) {
    __shared__ float sH1[HID*NB];        // [j*4+b]
    __shared__ float sred[4][8];
    int tid = threadIdx.x;
    #pragma unroll
    for (int i = 0; i < 8; ++i) {
        int jb = tid + i*256;
        int j = jb >> 2;
        float s = 0.f;
        #pragma unroll
        for (int k = 0; k < RSPLIT; ++k) s += part2[k*(HID*NB) + jb];
        s += b1[j];
        s = (s > 0.f) ? s : 0.01f*s;     // LeakyReLU(0.01)
        sH1[jb] = s;
    }
    __syncthreads();
    float p[8] = {};                      // [b*2+o]
    #pragma unroll
    for (int rep = 0; rep < 2; ++rep) {
        int j = tid + rep*256;
        float w0 = W2[j*NOUT], w1 = W2[j*NOUT+1];
        #pragma unroll
        for (int b = 0; b < NB; ++b) {
            float hv = sH1[j*4 + b];
            p[b*2]   += hv*w0;
            p[b*2+1] += hv*w1;
        }
    }
    int lane = tid & 63, wid = tid >> 6;
    #pragma unroll
    for (int i = 0; i < 8; ++i) {
        #pragma unroll
        for (int off = 32; off > 0; off >>= 1) p[i] += __shfl_xor(p[i], off);
    }
    if (lane == 0)
        #pragma unroll
        for (int i = 0; i < 8; ++i) sred[wid][i] = p[i];
    __syncthreads();
    if (tid < 8) {
        float s = sred[0][tid] + sred[1][tid] + sred[2][tid] + sred[3][tid];
        out[tid] = s + b2[tid & 1];
    }
}

// ---------------- launch ----------------

extern "C" void kernel_launch(void* const* d_in, const int* in_sizes, int n_in,
                              void* d_out, int out_size, void* d_ws, size_t ws_size,
                              hipStream_t stream) {
    const float* x   = (const float*)d_in[0];
    const int*   ei  = (const int*)d_in[1];
    const float* ew  = (const float*)d_in[2];
    const float* Wz  = (const float*)d_in[3];
    const float* bz  = (const float*)d_in[4];
    const float* Lz  = (const float*)d_in[5];
    const float* lbz = (const float*)d_in[6];
    const float* Wr  = (const float*)d_in[7];
    const float* br  = (const float*)d_in[8];
    const float* Lr  = (const float*)d_in[9];
    const float* lbr = (const float*)d_in[10];
    const float* Wh  = (const float*)d_in[11];
    const float* bh  = (const float*)d_in[12];
    const float* Lh  = (const float*)d_in[13];
    const float* lbh = (const float*)d_in[14];
    const float* W1  = (const float*)d_in[15];
    const float* b1  = (const float*)d_in[16];
    const float* W2  = (const float*)d_in[17];
    const float* b2  = (const float*)d_in[18];
    float* out = (float*)d_out;

    char* base = (char*)d_ws;
    size_t off = 0;
    auto alloc = [&](size_t bytes) -> char* {
        char* p = base + off;
        off = (off + bytes + 255) & ~(size_t)255;
        return p;
    };
    float*  dinv   = (float*)alloc(NN*sizeof(float));
    int*    count  = (int*)  alloc(NN*sizeof(int));
    int*    rowptr = (int*)  alloc((NN+1)*sizeof(int));
    int*    cursor = (int*)  alloc(NN*sizeof(int));
    int*    col    = (int*)  alloc(NE*sizeof(int));
    float*  val    = (float*)alloc(NE*sizeof(float));
    float4* xp     = (float4*)alloc((size_t)NT*NN*NB*sizeof(float4));
    float4* agg    = (float4*)alloc((size_t)NT*NB*NN*sizeof(float4));
    float*  H      = (float*)alloc((size_t)NB*NN*NC*sizeof(float));
    float*  part   = (float*)alloc((size_t)NPART*HID*NB*sizeof(float));
    float*  part2  = (float*)alloc((size_t)RSPLIT*HID*NB*sizeof(float));
    (void)ws_size; (void)n_in; (void)in_sizes; (void)out_size;

    k_init<<<(NN+255)/256, 256, 0, stream>>>(count, cursor);
    k_count<<<(NE+255)/256, 256, 0, stream>>>(ei, count);
    k_scan<<<1, 1024, 0, stream>>>(count, rowptr);
    k_fill<<<(NE+255)/256, 256, 0, stream>>>(ei, ew, rowptr, cursor, col, val);
    k_deg<<<(NN+255)/256, 256, 0, stream>>>(rowptr, val, dinv);
    k_norm<<<(NN+255)/256, 256, 0, stream>>>(rowptr, col, dinv, val);
    k_xpad<<<(NN*NT+255)/256, 256, 0, stream>>>(x, xp);
    k_agg<<<(NN*NT+255)/256, 256, 0, stream>>>(xp, rowptr, col, val, dinv, agg);
    k_gru_all<<<(NB*NN+255)/256, 256, 0, stream>>>(Wz, bz, Lz, lbz, Wr, br, Lr, lbr,
                                                   Wh, bh, Lh, lbh, agg, H);
    k_head1<<<NHB, 256, 0, stream>>>(H, W1, part);
    k_reduce1<<<(RSPLIT*HID*NB+255)/256, 256, 0, stream>>>(part, part2);
    k_reduce2final<<<1, 256, 0, stream>>>(part2, b1, W2, b2, out);
}